// Round 5
// baseline (474.112 us; speedup 1.0000x reference)
//
#include <hip/hip_runtime.h>
#include <hip/hip_bf16.h>

#define N_NODES 100000
#define N_EDGES 1600000
#define N_GRAPHS 128
#define IN_F 128
#define H_F 128
#define OUT_F 64
#define HID 10
#define NCLS 10
#define MAXDEG 64   // in-degree ~ Poisson(16); P(deg>64) ~ 1e-20 per node
#define XPAD 136    // LDS row stride in bf16 (pad 128 -> 136: 16-way bank conflict -> free 2-way)
#define NB_EDGE (N_EDGES / 256)   // 6250, exact
#define NB_PREP 16

typedef __attribute__((ext_vector_type(8))) short bf16x8;
typedef __attribute__((ext_vector_type(4))) float f32x4;

__device__ __forceinline__ float bl(unsigned int u) { return __uint_as_float(u << 16); }
__device__ __forceinline__ float bh(unsigned int u) { return __uint_as_float(u & 0xffff0000u); }

// ---------------- phase A: out-degree histogram (1 txn/edge) + weight transpose roles ----------------
__global__ void k_hist(const int* __restrict__ src, int* __restrict__ cnt_out,
                       const float* __restrict__ W1, const float* __restrict__ W2,
                       unsigned short* __restrict__ Wt1, unsigned short* __restrict__ Wt2) {
    int b = blockIdx.x;
    if (b < NB_EDGE) {
        int e = b * 256 + threadIdx.x;   // N_EDGES % 256 == 0
        atomicAdd(&cnt_out[src[e]], 1);
    } else {
        int t = (b - NB_EDGE) * 256 + threadIdx.x;
        const int stride = NB_PREP * 256;
        for (int i = t; i < 128 * 128; i += stride) {
            int c = i >> 7, k = i & 127;
            __hip_bfloat16 v = __float2bfloat16(W1[k * 128 + c]);
            Wt1[i] = *(unsigned short*)&v;
        }
        for (int i = t; i < 64 * 128; i += stride) {
            int c = i >> 7, k = i & 127;
            __hip_bfloat16 v = __float2bfloat16(W2[k * 64 + c]);
            Wt2[i] = *(unsigned short*)&v;
        }
    }
}

// ---------------- phase B: padded-CSR fill (2 txns/edge: ticket + store) ----------------
__global__ void k_fill(const int* __restrict__ src, const int* __restrict__ dst,
                       int* __restrict__ cnt_in, int* __restrict__ colsp) {
    int e = blockIdx.x * 256 + threadIdx.x;   // exact grid
    int s = src[e];
    int d = dst[e];
    int idx = atomicAdd(&cnt_in[d], 1);
    if (idx < MAXDEG) colsp[d * MAXDEG + idx] = s;
}

// ---------------- MFMA GEMM: G[v, cbase..+63] = rsqrt(deg_out[v]) * (X[v,:] @ W[:, cbase..+63])
template <int TOTF, bool XBF16>
__global__ __launch_bounds__(256) void k_gemm_mfma(const void* __restrict__ Xv,
                                                   const unsigned short* __restrict__ Wt,
                                                   const int* __restrict__ cnt_out,
                                                   unsigned short* __restrict__ Gout) {
    __shared__ __align__(16) unsigned short Xs[32 * XPAD];
    __shared__ __align__(16) unsigned short Ws[64 * XPAD];
    const int tid = threadIdx.x;
    const int cbase = blockIdx.y * 64;
    const int row0 = blockIdx.x * 32;  // N_NODES % 32 == 0

    if constexpr (XBF16) {
        const uint2* X2 = (const uint2*)Xv;  // row = 32 uint2 (128 bf16)
#pragma unroll
        for (int j = 0; j < 4; j++) {
            int i = tid + 256 * j;
            int r = i >> 5, kk = i & 31;
            uint2 u = X2[(size_t)(row0 + r) * 32 + kk];
            *(uint2*)&Xs[r * XPAD + kk * 4] = u;
        }
    } else {
        const float4* X4 = (const float4*)Xv;  // row = 32 float4
#pragma unroll
        for (int j = 0; j < 4; j++) {
            int i = tid + 256 * j;
            int r = i >> 5, k4 = i & 31;
            float4 x = X4[(size_t)(row0 + r) * 32 + k4];
            __hip_bfloat162 lo = __float22bfloat162_rn({x.x, x.y});
            __hip_bfloat162 hi = __float22bfloat162_rn({x.z, x.w});
            uint2 u;
            u.x = *(unsigned int*)&lo;
            u.y = *(unsigned int*)&hi;
            *(uint2*)&Xs[r * XPAD + k4 * 4] = u;
        }
    }
    {
        const uint2* W2 = (const uint2*)Wt;  // row = 32 uint2
#pragma unroll
        for (int j = 0; j < 8; j++) {
            int i = tid + 256 * j;
            int c = i >> 5, kk = i & 31;
            uint2 u = W2[(size_t)(cbase + c) * 32 + kk];
            *(uint2*)&Ws[c * XPAD + kk * 4] = u;
        }
    }
    __syncthreads();

    const int lane = tid & 63;
    const int wv = tid >> 6;
    const int m = lane & 15;
    const int q = lane >> 4;
    const int roff = (wv & 1) * 16;
    const int coff = (wv >> 1) * 32;

    f32x4 acc0 = {0.f, 0.f, 0.f, 0.f}, acc1 = {0.f, 0.f, 0.f, 0.f};
#pragma unroll
    for (int ks = 0; ks < 4; ks++) {
        int kb = ks * 32 + q * 8;
        bf16x8 a  = *(const bf16x8*)&Xs[(roff + m) * XPAD + kb];
        bf16x8 b0 = *(const bf16x8*)&Ws[(coff + m) * XPAD + kb];
        bf16x8 b1 = *(const bf16x8*)&Ws[(coff + 16 + m) * XPAD + kb];
        acc0 = __builtin_amdgcn_mfma_f32_16x16x32_bf16(a, b0, acc0, 0, 0, 0);
        acc1 = __builtin_amdgcn_mfma_f32_16x16x32_bf16(a, b1, acc1, 0, 0, 0);
    }
#pragma unroll
    for (int r = 0; r < 4; r++) {
        int row = row0 + roff + q * 4 + r;
        float s = rsqrtf((float)max(cnt_out[row], 1));
        int col0 = cbase + coff + m;
        __hip_bfloat16 o0 = __float2bfloat16(acc0[r] * s);
        __hip_bfloat16 o1 = __float2bfloat16(acc1[r] * s);
        Gout[(size_t)row * TOTF + col0]      = *(unsigned short*)&o0;
        Gout[(size_t)row * TOTF + col0 + 16] = *(unsigned short*)&o1;
    }
}

// ---------------- SpMM F=128: half-wave per neighbor, uint2 gathers ----------------
// H[v] = relu(rsqrt(deg_in[v]) * sum_{s} G[s] + bias), G/H bf16 rows of 128
__global__ __launch_bounds__(256) void k_spmm128(const uint2* __restrict__ G2,
                                                 const int* __restrict__ cnt_in,
                                                 const int* __restrict__ colsp,
                                                 const float* __restrict__ bias,
                                                 uint2* __restrict__ H2) {
    const int lane = threadIdx.x & 63;
    const int wave = threadIdx.x >> 6;
    const int v = blockIdx.x * 4 + wave;   // N_NODES % 4 == 0
    int cnt = cnt_in[v];
    int deg = min(cnt, MAXDEG);
    const int mycol = (lane < deg) ? colsp[v * MAXDEG + lane] : 0;
    const float r = rsqrtf((float)max(cnt, 1));
    const int c = lane & 31;   // uint2 index within row (feats 4c..4c+3)
    const int h = lane >> 5;   // half-wave id = neighbor sub-slot
    float ax = 0.f, ay = 0.f, az = 0.f, aw = 0.f;
    const int deg8 = deg & ~7;
    for (int j = 0; j < deg8; j += 8) {
        int s0 = __shfl(mycol, j + h);
        int s1 = __shfl(mycol, j + 2 + h);
        int s2 = __shfl(mycol, j + 4 + h);
        int s3 = __shfl(mycol, j + 6 + h);
        uint2 u0 = G2[(size_t)s0 * 32 + c];
        uint2 u1 = G2[(size_t)s1 * 32 + c];
        uint2 u2 = G2[(size_t)s2 * 32 + c];
        uint2 u3 = G2[(size_t)s3 * 32 + c];
        ax += (bl(u0.x) + bl(u1.x)) + (bl(u2.x) + bl(u3.x));
        ay += (bh(u0.x) + bh(u1.x)) + (bh(u2.x) + bh(u3.x));
        az += (bl(u0.y) + bl(u1.y)) + (bl(u2.y) + bl(u3.y));
        aw += (bh(u0.y) + bh(u1.y)) + (bh(u2.y) + bh(u3.y));
    }
    for (int j = deg8; j < deg; j += 2) {
        int idx = j + h;
        int sj = __shfl(mycol, min(idx, deg - 1));
        if (idx < deg) {
            uint2 u = G2[(size_t)sj * 32 + c];
            ax += bl(u.x); ay += bh(u.x); az += bl(u.y); aw += bh(u.y);
        }
    }
    ax += __shfl_xor(ax, 32);
    ay += __shfl_xor(ay, 32);
    az += __shfl_xor(az, 32);
    aw += __shfl_xor(aw, 32);
    if (h == 0) {
        float4 b = *(const float4*)&bias[4 * c];
        __hip_bfloat162 p0 = __float22bfloat162_rn({fmaxf(fmaf(ax, r, b.x), 0.f),
                                                    fmaxf(fmaf(ay, r, b.y), 0.f)});
        __hip_bfloat162 p1 = __float22bfloat162_rn({fmaxf(fmaf(az, r, b.z), 0.f),
                                                    fmaxf(fmaf(aw, r, b.w), 0.f)});
        uint2 o;
        o.x = *(unsigned int*)&p0;
        o.y = *(unsigned int*)&p1;
        H2[(size_t)v * 32 + c] = o;
    }
}

// ---------------- SpMM F=64: quarter-wave per neighbor, uint2 gathers ----------------
__global__ __launch_bounds__(256) void k_spmm64(const uint2* __restrict__ G2,
                                                const int* __restrict__ cnt_in,
                                                const int* __restrict__ colsp,
                                                const float* __restrict__ bias,
                                                uint2* __restrict__ H2) {
    const int lane = threadIdx.x & 63;
    const int wave = threadIdx.x >> 6;
    const int v = blockIdx.x * 4 + wave;
    int cnt = cnt_in[v];
    int deg = min(cnt, MAXDEG);
    const int mycol = (lane < deg) ? colsp[v * MAXDEG + lane] : 0;
    const float r = rsqrtf((float)max(cnt, 1));
    const int c = lane & 15;   // uint2 index within row (feats 4c..4c+3)
    const int h = lane >> 4;   // quarter-wave id
    float ax = 0.f, ay = 0.f, az = 0.f, aw = 0.f;
    const int deg16 = deg & ~15;
    for (int j = 0; j < deg16; j += 16) {
        int s0 = __shfl(mycol, j + h);
        int s1 = __shfl(mycol, j + 4 + h);
        int s2 = __shfl(mycol, j + 8 + h);
        int s3 = __shfl(mycol, j + 12 + h);
        uint2 u0 = G2[(size_t)s0 * 16 + c];
        uint2 u1 = G2[(size_t)s1 * 16 + c];
        uint2 u2 = G2[(size_t)s2 * 16 + c];
        uint2 u3 = G2[(size_t)s3 * 16 + c];
        ax += (bl(u0.x) + bl(u1.x)) + (bl(u2.x) + bl(u3.x));
        ay += (bh(u0.x) + bh(u1.x)) + (bh(u2.x) + bh(u3.x));
        az += (bl(u0.y) + bl(u1.y)) + (bl(u2.y) + bl(u3.y));
        aw += (bh(u0.y) + bh(u1.y)) + (bh(u2.y) + bh(u3.y));
    }
    for (int j = deg16; j < deg; j += 4) {
        int idx = j + h;
        int sj = __shfl(mycol, min(idx, deg - 1));
        if (idx < deg) {
            uint2 u = G2[(size_t)sj * 16 + c];
            ax += bl(u.x); ay += bh(u.x); az += bl(u.y); aw += bh(u.y);
        }
    }
    ax += __shfl_xor(ax, 16); ax += __shfl_xor(ax, 32);
    ay += __shfl_xor(ay, 16); ay += __shfl_xor(ay, 32);
    az += __shfl_xor(az, 16); az += __shfl_xor(az, 32);
    aw += __shfl_xor(aw, 16); aw += __shfl_xor(aw, 32);
    if (h == 0) {
        float4 b = *(const float4*)&bias[4 * c];
        __hip_bfloat162 p0 = __float22bfloat162_rn({fmaxf(fmaf(ax, r, b.x), 0.f),
                                                    fmaxf(fmaf(ay, r, b.y), 0.f)});
        __hip_bfloat162 p1 = __float22bfloat162_rn({fmaxf(fmaf(az, r, b.z), 0.f),
                                                    fmaxf(fmaf(aw, r, b.w), 0.f)});
        uint2 o;
        o.x = *(unsigned int*)&p0;
        o.y = *(unsigned int*)&p1;
        H2[(size_t)v * 16 + c] = o;
    }
}

// ---------------- fused pooling + MLP + softmax (block per graph; h2 bf16) ----------------
__global__ __launch_bounds__(256) void k_poolmlp(const unsigned short* __restrict__ h2,
                                                 const int* __restrict__ gid,
                                                 const float* __restrict__ fcW1,
                                                 const float* __restrict__ fcb1,
                                                 const float* __restrict__ fcW2,
                                                 const float* __restrict__ fcb2,
                                                 float* __restrict__ out) {
    __shared__ int se[2];
    __shared__ float part[4][64];
    __shared__ float p[64];
    __shared__ float z[10];
    __shared__ float l[10];
    __shared__ float red[2];
    const int g = blockIdx.x;
    const int tid = threadIdx.x;  // 256
    if (tid < 2) {
        int target = g + tid;  // lower_bound over sorted gid
        int lo = 0, hi = N_NODES;
        while (lo < hi) {
            int mid = (lo + hi) >> 1;
            if (gid[mid] < target) lo = mid + 1; else hi = mid;
        }
        se[tid] = lo;
    }
    __syncthreads();
    const int s = se[0], e = se[1];
    const int c = tid & 63;
    const int w = tid >> 6;
    float acc = 0.f;
    for (int v = s + w; v < e; v += 4)
        acc += __uint_as_float(((unsigned int)h2[(size_t)v * 64 + c]) << 16);
    part[w][c] = acc;
    __syncthreads();
    if (tid < 64) {
        float t = part[0][tid] + part[1][tid] + part[2][tid] + part[3][tid];
        p[tid] = t / (float)max(e - s, 1);
    }
    __syncthreads();
    if (tid < 10) {
        float a = fcb1[tid];
        for (int k = 0; k < 64; k++) a = fmaf(p[k], fcW1[k * 10 + tid], a);
        z[tid] = fmaxf(a, 0.f);
    }
    __syncthreads();
    if (tid < 10) {
        float a = fcb2[tid];
        for (int k = 0; k < 10; k++) a = fmaf(z[k], fcW2[k * 10 + tid], a);
        l[tid] = a;
    }
    __syncthreads();
    if (tid == 0) {
        float m = l[0];
        for (int i = 1; i < 10; i++) m = fmaxf(m, l[i]);
        float ssum = 0.f;
        for (int i = 0; i < 10; i++) ssum += expf(l[i] - m);
        red[0] = m;
        red[1] = ssum;
    }
    __syncthreads();
    if (tid < 10) out[g * 10 + tid] = expf(l[tid] - red[0]) / red[1];
}

// ---------------- host ----------------
extern "C" void kernel_launch(void* const* d_in, const int* in_sizes, int n_in,
                              void* d_out, int out_size, void* d_ws, size_t ws_size,
                              hipStream_t stream) {
    const float* feats = (const float*)d_in[0];
    const int* src = (const int*)d_in[1];
    const int* dst = (const int*)d_in[2];
    const int* gid = (const int*)d_in[3];
    const float* W1 = (const float*)d_in[4];
    const float* b1 = (const float*)d_in[5];
    const float* W2 = (const float*)d_in[6];
    const float* b2 = (const float*)d_in[7];
    const float* fcW1 = (const float*)d_in[8];
    const float* fcb1 = (const float*)d_in[9];
    const float* fcW2 = (const float*)d_in[10];
    const float* fcb2 = (const float*)d_in[11];
    float* out = (float*)d_out;

    char* w = (char*)d_ws;
    size_t off = 0;
    auto alloc = [&](size_t bytes) -> void* {
        void* p = w + off;
        off = (off + bytes + 255) & ~(size_t)255;
        return p;
    };
    int* cnt_out = (int*)alloc(N_NODES * 4 * 2);   // cnt_out + cnt_in adjacent (single memset)
    int* cnt_in  = cnt_out + N_NODES;
    int* colsp   = (int*)alloc((size_t)N_NODES * MAXDEG * 4);                // 25.6 MB
    unsigned short* Wt1 = (unsigned short*)alloc(128 * 128 * 2);
    unsigned short* Wt2 = (unsigned short*)alloc(64 * 128 * 2);
    unsigned short* g1 = (unsigned short*)alloc((size_t)N_NODES * 128 * 2);  // bf16
    unsigned short* h1 = (unsigned short*)alloc((size_t)N_NODES * 128 * 2);  // bf16
    unsigned short* g2 = (unsigned short*)alloc((size_t)N_NODES * 64 * 2);   // bf16
    unsigned short* h2 = (unsigned short*)alloc((size_t)N_NODES * 64 * 2);   // bf16

    hipMemsetAsync(cnt_out, 0, N_NODES * 4 * 2, stream);

    // phase A: out-degree histogram + bf16 transposed weights (role split)
    k_hist<<<NB_EDGE + NB_PREP, 256, 0, stream>>>(src, cnt_out, W1, W2, Wt1, Wt2);
    // layer-1 GEMM only needs cnt_out + Wt1
    k_gemm_mfma<128, false><<<dim3(N_NODES / 32, 2), 256, 0, stream>>>(feats, Wt1, cnt_out, g1);
    // phase B: in-degree ticket + padded-CSR fill
    k_fill<<<NB_EDGE, 256, 0, stream>>>(src, dst, cnt_in, colsp);

    k_spmm128<<<N_NODES / 4, 256, 0, stream>>>((const uint2*)g1, cnt_in, colsp, b1, (uint2*)h1);
    k_gemm_mfma<64, true><<<dim3(N_NODES / 32, 1), 256, 0, stream>>>(h1, Wt2, cnt_out, g2);
    k_spmm64<<<N_NODES / 4, 256, 0, stream>>>((const uint2*)g2, cnt_in, colsp, b2, (uint2*)h2);

    k_poolmlp<<<N_GRAPHS, 256, 0, stream>>>(h2, gid, fcW1, fcb1, fcW2, fcb2, out);
}

// Round 6
// 425.154 us; speedup vs baseline: 1.1152x; 1.1152x over previous
//
#include <hip/hip_runtime.h>
#include <hip/hip_bf16.h>

#define N_NODES 100000
#define N_EDGES 1600000
#define N_GRAPHS 128
#define IN_F 128
#define H_F 128
#define OUT_F 64
#define HID 10
#define NCLS 10
#define MAXDEG 64   // in-degree ~ Poisson(16); P(deg>64) ~ 1e-20 per node
#define XPAD 136    // LDS row stride in bf16 (pad 128 -> 136: 16-way conflict -> free 2-way)
#define ROWI 72     // adjacency row stride in ints: [0]=count, [8..71]=neighbors (288 B)
#define NB_EDGE (N_EDGES / 256)            // 6250, exact
#define NB_ZERO ((N_NODES + 255) / 256)    // 391
#define NB_PREP 16

typedef __attribute__((ext_vector_type(8))) short bf16x8;
typedef __attribute__((ext_vector_type(4))) float f32x4;

__device__ __forceinline__ float bl(unsigned int u) { return __uint_as_float(u << 16); }
__device__ __forceinline__ float bh(unsigned int u) { return __uint_as_float(u & 0xffff0000u); }

// ---------------- pre-pass: zero adjacency count slots + bf16 transposed weights ----------------
__global__ void k_zero_prep(int* __restrict__ colsp,
                            const float* __restrict__ W1, const float* __restrict__ W2,
                            unsigned short* __restrict__ Wt1, unsigned short* __restrict__ Wt2) {
    int b = blockIdx.x;
    if (b < NB_ZERO) {
        int v = b * 256 + threadIdx.x;
        if (v < N_NODES) colsp[v * ROWI] = 0;
    } else {
        int t = (b - NB_ZERO) * 256 + threadIdx.x;
        const int stride = NB_PREP * 256;
        for (int i = t; i < 128 * 128; i += stride) {
            int c = i >> 7, k = i & 127;
            __hip_bfloat16 v = __float2bfloat16(W1[k * 128 + c]);
            Wt1[i] = *(unsigned short*)&v;
        }
        for (int i = t; i < 64 * 128; i += stride) {
            int c = i >> 7, k = i & 127;
            __hip_bfloat16 v = __float2bfloat16(W2[k * 64 + c]);
            Wt2[i] = *(unsigned short*)&v;
        }
    }
}

// ---------------- single-pass build: out-degree histogram + co-located ticket/fill ----------------
__global__ void k_build(const int* __restrict__ src, const int* __restrict__ dst,
                        int* __restrict__ cnt_out, int* __restrict__ colsp) {
    int e = blockIdx.x * 256 + threadIdx.x;   // exact grid
    int s = src[e];
    int d = dst[e];
    atomicAdd(&cnt_out[s], 1);
    int idx = atomicAdd(&colsp[d * ROWI], 1);       // ticket lives in the adjacency row
    if (idx < MAXDEG) colsp[d * ROWI + 8 + idx] = s;  // store hits the same 288 B sector
}

// ---------------- MFMA GEMM: G[v, cbase..+63] = rsqrt(deg_out[v]) * (X[v,:] @ W[:, cbase..+63])
template <int TOTF, bool XBF16>
__global__ __launch_bounds__(256) void k_gemm_mfma(const void* __restrict__ Xv,
                                                   const unsigned short* __restrict__ Wt,
                                                   const int* __restrict__ cnt_out,
                                                   unsigned short* __restrict__ Gout) {
    __shared__ __align__(16) unsigned short Xs[32 * XPAD];
    __shared__ __align__(16) unsigned short Ws[64 * XPAD];
    const int tid = threadIdx.x;
    const int cbase = blockIdx.y * 64;
    const int row0 = blockIdx.x * 32;  // N_NODES % 32 == 0

    if constexpr (XBF16) {
        const uint2* X2 = (const uint2*)Xv;  // row = 32 uint2 (128 bf16)
#pragma unroll
        for (int j = 0; j < 4; j++) {
            int i = tid + 256 * j;
            int r = i >> 5, kk = i & 31;
            uint2 u = X2[(size_t)(row0 + r) * 32 + kk];
            *(uint2*)&Xs[r * XPAD + kk * 4] = u;
        }
    } else {
        const float4* X4 = (const float4*)Xv;  // row = 32 float4
#pragma unroll
        for (int j = 0; j < 4; j++) {
            int i = tid + 256 * j;
            int r = i >> 5, k4 = i & 31;
            float4 x = X4[(size_t)(row0 + r) * 32 + k4];
            __hip_bfloat162 lo = __float22bfloat162_rn({x.x, x.y});
            __hip_bfloat162 hi = __float22bfloat162_rn({x.z, x.w});
            uint2 u;
            u.x = *(unsigned int*)&lo;
            u.y = *(unsigned int*)&hi;
            *(uint2*)&Xs[r * XPAD + k4 * 4] = u;
        }
    }
    {
        const uint2* W2 = (const uint2*)Wt;  // row = 32 uint2
#pragma unroll
        for (int j = 0; j < 8; j++) {
            int i = tid + 256 * j;
            int c = i >> 5, kk = i & 31;
            uint2 u = W2[(size_t)(cbase + c) * 32 + kk];
            *(uint2*)&Ws[c * XPAD + kk * 4] = u;
        }
    }
    __syncthreads();

    const int lane = tid & 63;
    const int wv = tid >> 6;
    const int m = lane & 15;
    const int q = lane >> 4;
    const int roff = (wv & 1) * 16;
    const int coff = (wv >> 1) * 32;

    f32x4 acc0 = {0.f, 0.f, 0.f, 0.f}, acc1 = {0.f, 0.f, 0.f, 0.f};
#pragma unroll
    for (int ks = 0; ks < 4; ks++) {
        int kb = ks * 32 + q * 8;
        bf16x8 a  = *(const bf16x8*)&Xs[(roff + m) * XPAD + kb];
        bf16x8 b0 = *(const bf16x8*)&Ws[(coff + m) * XPAD + kb];
        bf16x8 b1 = *(const bf16x8*)&Ws[(coff + 16 + m) * XPAD + kb];
        acc0 = __builtin_amdgcn_mfma_f32_16x16x32_bf16(a, b0, acc0, 0, 0, 0);
        acc1 = __builtin_amdgcn_mfma_f32_16x16x32_bf16(a, b1, acc1, 0, 0, 0);
    }
#pragma unroll
    for (int r = 0; r < 4; r++) {
        int row = row0 + roff + q * 4 + r;
        float s = rsqrtf((float)max(cnt_out[row], 1));
        int col0 = cbase + coff + m;
        __hip_bfloat16 o0 = __float2bfloat16(acc0[r] * s);
        __hip_bfloat16 o1 = __float2bfloat16(acc1[r] * s);
        Gout[(size_t)row * TOTF + col0]      = *(unsigned short*)&o0;
        Gout[(size_t)row * TOTF + col0 + 16] = *(unsigned short*)&o1;
    }
}

// ---------------- SpMM F=128: half-wave per neighbor, uint2 gathers ----------------
__global__ __launch_bounds__(256) void k_spmm128(const uint2* __restrict__ G2,
                                                 const int* __restrict__ colsp,
                                                 const float* __restrict__ bias,
                                                 uint2* __restrict__ H2) {
    const int lane = threadIdx.x & 63;
    const int wave = threadIdx.x >> 6;
    const int v = blockIdx.x * 4 + wave;   // N_NODES % 4 == 0
    const int* row = &colsp[(size_t)v * ROWI];
    int cnt = row[0];
    int deg = min(cnt, MAXDEG);
    const int mycol = (lane < deg) ? row[8 + lane] : 0;
    const float r = rsqrtf((float)max(cnt, 1));
    const int c = lane & 31;   // uint2 index within row (feats 4c..4c+3)
    const int h = lane >> 5;   // half-wave id = neighbor sub-slot
    float ax = 0.f, ay = 0.f, az = 0.f, aw = 0.f;
    const int deg8 = deg & ~7;
    for (int j = 0; j < deg8; j += 8) {
        int s0 = __shfl(mycol, j + h);
        int s1 = __shfl(mycol, j + 2 + h);
        int s2 = __shfl(mycol, j + 4 + h);
        int s3 = __shfl(mycol, j + 6 + h);
        uint2 u0 = G2[(size_t)s0 * 32 + c];
        uint2 u1 = G2[(size_t)s1 * 32 + c];
        uint2 u2 = G2[(size_t)s2 * 32 + c];
        uint2 u3 = G2[(size_t)s3 * 32 + c];
        ax += (bl(u0.x) + bl(u1.x)) + (bl(u2.x) + bl(u3.x));
        ay += (bh(u0.x) + bh(u1.x)) + (bh(u2.x) + bh(u3.x));
        az += (bl(u0.y) + bl(u1.y)) + (bl(u2.y) + bl(u3.y));
        aw += (bh(u0.y) + bh(u1.y)) + (bh(u2.y) + bh(u3.y));
    }
    for (int j = deg8; j < deg; j += 2) {
        int idx = j + h;
        int sj = __shfl(mycol, min(idx, deg - 1));
        if (idx < deg) {
            uint2 u = G2[(size_t)sj * 32 + c];
            ax += bl(u.x); ay += bh(u.x); az += bl(u.y); aw += bh(u.y);
        }
    }
    ax += __shfl_xor(ax, 32);
    ay += __shfl_xor(ay, 32);
    az += __shfl_xor(az, 32);
    aw += __shfl_xor(aw, 32);
    if (h == 0) {
        float4 b = *(const float4*)&bias[4 * c];
        __hip_bfloat162 p0 = __float22bfloat162_rn({fmaxf(fmaf(ax, r, b.x), 0.f),
                                                    fmaxf(fmaf(ay, r, b.y), 0.f)});
        __hip_bfloat162 p1 = __float22bfloat162_rn({fmaxf(fmaf(az, r, b.z), 0.f),
                                                    fmaxf(fmaf(aw, r, b.w), 0.f)});
        uint2 o;
        o.x = *(unsigned int*)&p0;
        o.y = *(unsigned int*)&p1;
        H2[(size_t)v * 32 + c] = o;
    }
}

// ---------------- SpMM F=64: quarter-wave per neighbor, uint2 gathers ----------------
__global__ __launch_bounds__(256) void k_spmm64(const uint2* __restrict__ G2,
                                                const int* __restrict__ colsp,
                                                const float* __restrict__ bias,
                                                uint2* __restrict__ H2) {
    const int lane = threadIdx.x & 63;
    const int wave = threadIdx.x >> 6;
    const int v = blockIdx.x * 4 + wave;
    const int* row = &colsp[(size_t)v * ROWI];
    int cnt = row[0];
    int deg = min(cnt, MAXDEG);
    const int mycol = (lane < deg) ? row[8 + lane] : 0;
    const float r = rsqrtf((float)max(cnt, 1));
    const int c = lane & 15;   // uint2 index within row
    const int h = lane >> 4;   // quarter-wave id
    float ax = 0.f, ay = 0.f, az = 0.f, aw = 0.f;
    const int deg16 = deg & ~15;
    for (int j = 0; j < deg16; j += 16) {
        int s0 = __shfl(mycol, j + h);
        int s1 = __shfl(mycol, j + 4 + h);
        int s2 = __shfl(mycol, j + 8 + h);
        int s3 = __shfl(mycol, j + 12 + h);
        uint2 u0 = G2[(size_t)s0 * 16 + c];
        uint2 u1 = G2[(size_t)s1 * 16 + c];
        uint2 u2 = G2[(size_t)s2 * 16 + c];
        uint2 u3 = G2[(size_t)s3 * 16 + c];
        ax += (bl(u0.x) + bl(u1.x)) + (bl(u2.x) + bl(u3.x));
        ay += (bh(u0.x) + bh(u1.x)) + (bh(u2.x) + bh(u3.x));
        az += (bl(u0.y) + bl(u1.y)) + (bl(u2.y) + bl(u3.y));
        aw += (bh(u0.y) + bh(u1.y)) + (bh(u2.y) + bh(u3.y));
    }
    for (int j = deg16; j < deg; j += 4) {
        int idx = j + h;
        int sj = __shfl(mycol, min(idx, deg - 1));
        if (idx < deg) {
            uint2 u = G2[(size_t)sj * 16 + c];
            ax += bl(u.x); ay += bh(u.x); az += bl(u.y); aw += bh(u.y);
        }
    }
    ax += __shfl_xor(ax, 16); ax += __shfl_xor(ax, 32);
    ay += __shfl_xor(ay, 16); ay += __shfl_xor(ay, 32);
    az += __shfl_xor(az, 16); az += __shfl_xor(az, 32);
    aw += __shfl_xor(aw, 16); aw += __shfl_xor(aw, 32);
    if (h == 0) {
        float4 b = *(const float4*)&bias[4 * c];
        __hip_bfloat162 p0 = __float22bfloat162_rn({fmaxf(fmaf(ax, r, b.x), 0.f),
                                                    fmaxf(fmaf(ay, r, b.y), 0.f)});
        __hip_bfloat162 p1 = __float22bfloat162_rn({fmaxf(fmaf(az, r, b.z), 0.f),
                                                    fmaxf(fmaf(aw, r, b.w), 0.f)});
        uint2 o;
        o.x = *(unsigned int*)&p0;
        o.y = *(unsigned int*)&p1;
        H2[(size_t)v * 16 + c] = o;
    }
}

// ---------------- fused pooling + MLP + softmax (block per graph; h2 bf16) ----------------
__global__ __launch_bounds__(256) void k_poolmlp(const unsigned short* __restrict__ h2,
                                                 const int* __restrict__ gid,
                                                 const float* __restrict__ fcW1,
                                                 const float* __restrict__ fcb1,
                                                 const float* __restrict__ fcW2,
                                                 const float* __restrict__ fcb2,
                                                 float* __restrict__ out) {
    __shared__ int se[2];
    __shared__ float part[4][64];
    __shared__ float p[64];
    __shared__ float z[10];
    __shared__ float l[10];
    __shared__ float red[2];
    const int g = blockIdx.x;
    const int tid = threadIdx.x;  // 256
    if (tid < 2) {
        int target = g + tid;  // lower_bound over sorted gid
        int lo = 0, hi = N_NODES;
        while (lo < hi) {
            int mid = (lo + hi) >> 1;
            if (gid[mid] < target) lo = mid + 1; else hi = mid;
        }
        se[tid] = lo;
    }
    __syncthreads();
    const int s = se[0], e = se[1];
    const int c = tid & 63;
    const int w = tid >> 6;
    float acc = 0.f;
    for (int v = s + w; v < e; v += 4)
        acc += __uint_as_float(((unsigned int)h2[(size_t)v * 64 + c]) << 16);
    part[w][c] = acc;
    __syncthreads();
    if (tid < 64) {
        float t = part[0][tid] + part[1][tid] + part[2][tid] + part[3][tid];
        p[tid] = t / (float)max(e - s, 1);
    }
    __syncthreads();
    if (tid < 10) {
        float a = fcb1[tid];
        for (int k = 0; k < 64; k++) a = fmaf(p[k], fcW1[k * 10 + tid], a);
        z[tid] = fmaxf(a, 0.f);
    }
    __syncthreads();
    if (tid < 10) {
        float a = fcb2[tid];
        for (int k = 0; k < 10; k++) a = fmaf(z[k], fcW2[k * 10 + tid], a);
        l[tid] = a;
    }
    __syncthreads();
    if (tid == 0) {
        float m = l[0];
        for (int i = 1; i < 10; i++) m = fmaxf(m, l[i]);
        float ssum = 0.f;
        for (int i = 0; i < 10; i++) ssum += expf(l[i] - m);
        red[0] = m;
        red[1] = ssum;
    }
    __syncthreads();
    if (tid < 10) out[g * 10 + tid] = expf(l[tid] - red[0]) / red[1];
}

// ---------------- host ----------------
extern "C" void kernel_launch(void* const* d_in, const int* in_sizes, int n_in,
                              void* d_out, int out_size, void* d_ws, size_t ws_size,
                              hipStream_t stream) {
    const float* feats = (const float*)d_in[0];
    const int* src = (const int*)d_in[1];
    const int* dst = (const int*)d_in[2];
    const int* gid = (const int*)d_in[3];
    const float* W1 = (const float*)d_in[4];
    const float* b1 = (const float*)d_in[5];
    const float* W2 = (const float*)d_in[6];
    const float* b2 = (const float*)d_in[7];
    const float* fcW1 = (const float*)d_in[8];
    const float* fcb1 = (const float*)d_in[9];
    const float* fcW2 = (const float*)d_in[10];
    const float* fcb2 = (const float*)d_in[11];
    float* out = (float*)d_out;

    char* w = (char*)d_ws;
    size_t off = 0;
    auto alloc = [&](size_t bytes) -> void* {
        void* p = w + off;
        off = (off + bytes + 255) & ~(size_t)255;
        return p;
    };
    int* cnt_out = (int*)alloc(N_NODES * 4);
    int* colsp   = (int*)alloc((size_t)N_NODES * ROWI * 4);                  // 28.8 MB
    unsigned short* Wt1 = (unsigned short*)alloc(128 * 128 * 2);
    unsigned short* Wt2 = (unsigned short*)alloc(64 * 128 * 2);
    unsigned short* g1 = (unsigned short*)alloc((size_t)N_NODES * 128 * 2);  // bf16
    unsigned short* h1 = (unsigned short*)alloc((size_t)N_NODES * 128 * 2);  // bf16
    unsigned short* g2 = (unsigned short*)alloc((size_t)N_NODES * 64 * 2);   // bf16
    unsigned short* h2 = (unsigned short*)alloc((size_t)N_NODES * 64 * 2);   // bf16

    hipMemsetAsync(cnt_out, 0, N_NODES * 4, stream);

    // pre-pass: zero count slots + bf16 transposed weights (role split)
    k_zero_prep<<<NB_ZERO + NB_PREP, 256, 0, stream>>>(colsp, W1, W2, Wt1, Wt2);
    // single-pass build: out-degree histogram + co-located ticket/fill
    k_build<<<NB_EDGE, 256, 0, stream>>>(src, dst, cnt_out, colsp);

    // layer 1
    k_gemm_mfma<128, false><<<dim3(N_NODES / 32, 2), 256, 0, stream>>>(feats, Wt1, cnt_out, g1);
    k_spmm128<<<N_NODES / 4, 256, 0, stream>>>((const uint2*)g1, colsp, b1, (uint2*)h1);

    // layer 2
    k_gemm_mfma<64, true><<<dim3(N_NODES / 32, 1), 256, 0, stream>>>(h1, Wt2, cnt_out, g2);
    k_spmm64<<<N_NODES / 4, 256, 0, stream>>>((const uint2*)g2, colsp, b2, (uint2*)h2);

    k_poolmlp<<<N_GRAPHS, 256, 0, stream>>>(h2, gid, fcW1, fcb1, fcW2, fcb2, out);
}

// Round 7
// 399.131 us; speedup vs baseline: 1.1879x; 1.0652x over previous
//
#include <hip/hip_runtime.h>
#include <hip/hip_bf16.h>

#define N_NODES 100000
#define N_EDGES 1600000
#define N_GRAPHS 128
#define IN_F 128
#define H_F 128
#define OUT_F 64
#define HID 10
#define NCLS 10
#define MAXDEG 64   // in-degree ~ Poisson(16); P(deg>64) ~ 1e-20 per node
#define XPAD 136    // LDS row stride in bf16 (pad 128 -> 136: 16-way conflict -> free 2-way)
#define ROWI 72     // adjacency row stride in ints: [0]=count, [8..71]=neighbors (288 B)
#define BSH 7                     // bucket = node >> 7 (128-node windows)
#define NBUCK 782                 // ceil(100000/128)
#define SBLK 128                  // edge blocks for hist/scatter
#define EPB (N_EDGES / SBLK)      // 12500, exact
#define NB_PREP 8

typedef __attribute__((ext_vector_type(8))) short bf16x8;
typedef __attribute__((ext_vector_type(4))) float f32x4;

__device__ __forceinline__ float bl(unsigned int u) { return __uint_as_float(u << 16); }
__device__ __forceinline__ float bh(unsigned int u) { return __uint_as_float(u & 0xffff0000u); }

// ---------------- phase 1: LDS-privatized bucket histograms (dst & src) + weight prep ----------------
__global__ __launch_bounds__(256) void k_hist2(const int* __restrict__ src, const int* __restrict__ dst,
                                               int* __restrict__ Pd, int* __restrict__ Ps,
                                               const float* __restrict__ W1, const float* __restrict__ W2,
                                               unsigned short* __restrict__ Wt1, unsigned short* __restrict__ Wt2) {
    __shared__ int hd[NBUCK];
    __shared__ int hs[NBUCK];
    const int blk = blockIdx.x;
    if (blk < SBLK) {
        for (int i = threadIdx.x; i < NBUCK; i += 256) { hd[i] = 0; hs[i] = 0; }
        __syncthreads();
        const int base = blk * EPB;
        for (int i = threadIdx.x; i < EPB; i += 256) {
            atomicAdd(&hd[dst[base + i] >> BSH], 1);
            atomicAdd(&hs[src[base + i] >> BSH], 1);
        }
        __syncthreads();
        for (int b = threadIdx.x; b < NBUCK; b += 256) {
            Pd[b * SBLK + blk] = hd[b];
            Ps[b * SBLK + blk] = hs[b];
        }
    } else {
        int t = (blk - SBLK) * 256 + threadIdx.x;
        const int stride = NB_PREP * 256;
        for (int i = t; i < 128 * 128; i += stride) {
            int c = i >> 7, k = i & 127;
            __hip_bfloat16 v = __float2bfloat16(W1[k * 128 + c]);
            Wt1[i] = *(unsigned short*)&v;
        }
        for (int i = t; i < 64 * 128; i += stride) {
            int c = i >> 7, k = i & 127;
            __hip_bfloat16 v = __float2bfloat16(W2[k * 64 + c]);
            Wt2[i] = *(unsigned short*)&v;
        }
    }
}

// ---------------- phase 2a: per-bucket scan across blocks (exclusive), emit totals ----------------
__global__ __launch_bounds__(128) void k_scanA(int* __restrict__ Pd, int* __restrict__ Ps,
                                               int* __restrict__ Td, int* __restrict__ Ts) {
    __shared__ int sc[128];
    const int b = blockIdx.x;
    const int t = threadIdx.x;
    int* P = (b < NBUCK) ? Pd : Ps;
    int* T = (b < NBUCK) ? Td : Ts;
    const int bb = (b < NBUCK) ? b : b - NBUCK;
    int v = P[bb * SBLK + t];
    sc[t] = v;
    __syncthreads();
    for (int off = 1; off < 128; off <<= 1) {
        int u = (t >= off) ? sc[t - off] : 0;
        __syncthreads();
        sc[t] += u;
        __syncthreads();
    }
    P[bb * SBLK + t] = sc[t] - v;    // exclusive within bucket
    if (t == 127) T[bb] = sc[127];
}

// ---------------- phase 2b: scan bucket totals -> global bases (with total at [NBUCK]) ----------------
__global__ __launch_bounds__(1024) void k_scanB(const int* __restrict__ Td, const int* __restrict__ Ts,
                                                int* __restrict__ Bd, int* __restrict__ Bs) {
    __shared__ int sc[1024];
    const int t = threadIdx.x;
    // dst
    int v = (t < NBUCK) ? Td[t] : 0;
    sc[t] = v;
    __syncthreads();
    for (int off = 1; off < 1024; off <<= 1) {
        int u = (t >= off) ? sc[t - off] : 0;
        __syncthreads();
        sc[t] += u;
        __syncthreads();
    }
    if (t < NBUCK) Bd[t] = sc[t] - v;
    if (t == NBUCK - 1) Bd[NBUCK] = sc[t];
    __syncthreads();
    // src
    int v2 = (t < NBUCK) ? Ts[t] : 0;
    sc[t] = v2;
    __syncthreads();
    for (int off = 1; off < 1024; off <<= 1) {
        int u = (t >= off) ? sc[t - off] : 0;
        __syncthreads();
        sc[t] += u;
        __syncthreads();
    }
    if (t < NBUCK) Bs[t] = sc[t] - v2;
    if (t == NBUCK - 1) Bs[NBUCK] = sc[t];
}

// ---------------- phase 3: bucketed scatter (clustered writes per (bucket,block)) ----------------
__global__ __launch_bounds__(256) void k_scatter(const int* __restrict__ src, const int* __restrict__ dst,
                                                 const int* __restrict__ Pd, const int* __restrict__ Ps,
                                                 const int* __restrict__ Bd, const int* __restrict__ Bs,
                                                 uint2* __restrict__ pb, int* __restrict__ sb) {
    __shared__ int td[NBUCK];
    __shared__ int ts[NBUCK];
    const int blk = blockIdx.x;
    for (int i = threadIdx.x; i < NBUCK; i += 256) { td[i] = 0; ts[i] = 0; }
    __syncthreads();
    const int base = blk * EPB;
    for (int i = threadIdx.x; i < EPB; i += 256) {
        int d = dst[base + i];
        int s = src[base + i];
        int bd = d >> BSH;
        int bs = s >> BSH;
        int tkd = atomicAdd(&td[bd], 1);
        pb[Bd[bd] + Pd[bd * SBLK + blk] + tkd] = make_uint2((unsigned)d, (unsigned)s);
        int tks = atomicAdd(&ts[bs], 1);
        sb[Bs[bs] + Ps[bs * SBLK + blk] + tks] = s;
    }
}

// ---------------- phase 4: per-window adjacency build in LDS + coalesced writeout + cnt_out ----------------
__global__ __launch_bounds__(256) void k_finalize(const uint2* __restrict__ pb, const int* __restrict__ Bd,
                                                  const int* __restrict__ sb, const int* __restrict__ Bs,
                                                  int* __restrict__ colsp, int* __restrict__ cnt_out) {
    __shared__ int cnt[128];
    __shared__ int adj[128 * 65];   // stride 65 spreads LDS banks
    __shared__ int h[128];
    const int b = blockIdx.x;
    const int tid = threadIdx.x;
    if (tid < 128) { cnt[tid] = 0; h[tid] = 0; }
    __syncthreads();
    // adjacency from dst-bucketed pairs
    {
        const int s0 = Bd[b], s1 = Bd[b + 1];
        for (int i = s0 + tid; i < s1; i += 256) {
            uint2 p = pb[i];
            int loc = p.x & 127;
            int t = atomicAdd(&cnt[loc], 1);
            if (t < MAXDEG) adj[loc * 65 + t] = (int)p.y;
        }
    }
    // out-degree histogram from src-bucketed values
    {
        const int s0 = Bs[b], s1 = Bs[b + 1];
        for (int i = s0 + tid; i < s1; i += 256)
            atomicAdd(&h[sb[i] & 127], 1);
    }
    __syncthreads();
    const int node0 = b << BSH;
    for (int i = tid; i < 128 * ROWI; i += 256) {
        int row = i / ROWI;
        int slot = i - row * ROWI;
        int node = node0 + row;
        if (node >= N_NODES) continue;
        int val = (slot == 0) ? cnt[row] : ((slot >= 8) ? adj[row * 65 + (slot - 8)] : 0);
        colsp[(size_t)node * ROWI + slot] = val;
    }
    int node = node0 + tid;
    if (tid < 128 && node < N_NODES) cnt_out[node] = h[tid];
}

// ---------------- MFMA GEMM: G[v, cbase..+63] = rsqrt(deg_out[v]) * (X[v,:] @ W[:, cbase..+63])
template <int TOTF, bool XBF16>
__global__ __launch_bounds__(256) void k_gemm_mfma(const void* __restrict__ Xv,
                                                   const unsigned short* __restrict__ Wt,
                                                   const int* __restrict__ cnt_out,
                                                   unsigned short* __restrict__ Gout) {
    __shared__ __align__(16) unsigned short Xs[32 * XPAD];
    __shared__ __align__(16) unsigned short Ws[64 * XPAD];
    const int tid = threadIdx.x;
    const int cbase = blockIdx.y * 64;
    const int row0 = blockIdx.x * 32;  // N_NODES % 32 == 0

    if constexpr (XBF16) {
        const uint2* X2 = (const uint2*)Xv;  // row = 32 uint2 (128 bf16)
#pragma unroll
        for (int j = 0; j < 4; j++) {
            int i = tid + 256 * j;
            int r = i >> 5, kk = i & 31;
            uint2 u = X2[(size_t)(row0 + r) * 32 + kk];
            *(uint2*)&Xs[r * XPAD + kk * 4] = u;
        }
    } else {
        const float4* X4 = (const float4*)Xv;  // row = 32 float4
#pragma unroll
        for (int j = 0; j < 4; j++) {
            int i = tid + 256 * j;
            int r = i >> 5, k4 = i & 31;
            float4 x = X4[(size_t)(row0 + r) * 32 + k4];
            __hip_bfloat162 lo = __float22bfloat162_rn({x.x, x.y});
            __hip_bfloat162 hi = __float22bfloat162_rn({x.z, x.w});
            uint2 u;
            u.x = *(unsigned int*)&lo;
            u.y = *(unsigned int*)&hi;
            *(uint2*)&Xs[r * XPAD + k4 * 4] = u;
        }
    }
    {
        const uint2* W2 = (const uint2*)Wt;  // row = 32 uint2
#pragma unroll
        for (int j = 0; j < 8; j++) {
            int i = tid + 256 * j;
            int c = i >> 5, kk = i & 31;
            uint2 u = W2[(size_t)(cbase + c) * 32 + kk];
            *(uint2*)&Ws[c * XPAD + kk * 4] = u;
        }
    }
    __syncthreads();

    const int lane = tid & 63;
    const int wv = tid >> 6;
    const int m = lane & 15;
    const int q = lane >> 4;
    const int roff = (wv & 1) * 16;
    const int coff = (wv >> 1) * 32;

    f32x4 acc0 = {0.f, 0.f, 0.f, 0.f}, acc1 = {0.f, 0.f, 0.f, 0.f};
#pragma unroll
    for (int ks = 0; ks < 4; ks++) {
        int kb = ks * 32 + q * 8;
        bf16x8 a  = *(const bf16x8*)&Xs[(roff + m) * XPAD + kb];
        bf16x8 b0 = *(const bf16x8*)&Ws[(coff + m) * XPAD + kb];
        bf16x8 b1 = *(const bf16x8*)&Ws[(coff + 16 + m) * XPAD + kb];
        acc0 = __builtin_amdgcn_mfma_f32_16x16x32_bf16(a, b0, acc0, 0, 0, 0);
        acc1 = __builtin_amdgcn_mfma_f32_16x16x32_bf16(a, b1, acc1, 0, 0, 0);
    }
#pragma unroll
    for (int r = 0; r < 4; r++) {
        int row = row0 + roff + q * 4 + r;
        float s = rsqrtf((float)max(cnt_out[row], 1));
        int col0 = cbase + coff + m;
        __hip_bfloat16 o0 = __float2bfloat16(acc0[r] * s);
        __hip_bfloat16 o1 = __float2bfloat16(acc1[r] * s);
        Gout[(size_t)row * TOTF + col0]      = *(unsigned short*)&o0;
        Gout[(size_t)row * TOTF + col0 + 16] = *(unsigned short*)&o1;
    }
}

// ---------------- SpMM F=128: half-wave per neighbor, uint2 gathers ----------------
__global__ __launch_bounds__(256) void k_spmm128(const uint2* __restrict__ G2,
                                                 const int* __restrict__ colsp,
                                                 const float* __restrict__ bias,
                                                 uint2* __restrict__ H2) {
    const int lane = threadIdx.x & 63;
    const int wave = threadIdx.x >> 6;
    const int v = blockIdx.x * 4 + wave;   // N_NODES % 4 == 0
    const int* row = &colsp[(size_t)v * ROWI];
    int cnt = row[0];
    int deg = min(cnt, MAXDEG);
    const int mycol = (lane < deg) ? row[8 + lane] : 0;
    const float r = rsqrtf((float)max(cnt, 1));
    const int c = lane & 31;
    const int h = lane >> 5;
    float ax = 0.f, ay = 0.f, az = 0.f, aw = 0.f;
    const int deg8 = deg & ~7;
    for (int j = 0; j < deg8; j += 8) {
        int s0 = __shfl(mycol, j + h);
        int s1 = __shfl(mycol, j + 2 + h);
        int s2 = __shfl(mycol, j + 4 + h);
        int s3 = __shfl(mycol, j + 6 + h);
        uint2 u0 = G2[(size_t)s0 * 32 + c];
        uint2 u1 = G2[(size_t)s1 * 32 + c];
        uint2 u2 = G2[(size_t)s2 * 32 + c];
        uint2 u3 = G2[(size_t)s3 * 32 + c];
        ax += (bl(u0.x) + bl(u1.x)) + (bl(u2.x) + bl(u3.x));
        ay += (bh(u0.x) + bh(u1.x)) + (bh(u2.x) + bh(u3.x));
        az += (bl(u0.y) + bl(u1.y)) + (bl(u2.y) + bl(u3.y));
        aw += (bh(u0.y) + bh(u1.y)) + (bh(u2.y) + bh(u3.y));
    }
    for (int j = deg8; j < deg; j += 2) {
        int idx = j + h;
        int sj = __shfl(mycol, min(idx, deg - 1));
        if (idx < deg) {
            uint2 u = G2[(size_t)sj * 32 + c];
            ax += bl(u.x); ay += bh(u.x); az += bl(u.y); aw += bh(u.y);
        }
    }
    ax += __shfl_xor(ax, 32);
    ay += __shfl_xor(ay, 32);
    az += __shfl_xor(az, 32);
    aw += __shfl_xor(aw, 32);
    if (h == 0) {
        float4 b = *(const float4*)&bias[4 * c];
        __hip_bfloat162 p0 = __float22bfloat162_rn({fmaxf(fmaf(ax, r, b.x), 0.f),
                                                    fmaxf(fmaf(ay, r, b.y), 0.f)});
        __hip_bfloat162 p1 = __float22bfloat162_rn({fmaxf(fmaf(az, r, b.z), 0.f),
                                                    fmaxf(fmaf(aw, r, b.w), 0.f)});
        uint2 o;
        o.x = *(unsigned int*)&p0;
        o.y = *(unsigned int*)&p1;
        H2[(size_t)v * 32 + c] = o;
    }
}

// ---------------- SpMM F=64: quarter-wave per neighbor, uint2 gathers ----------------
__global__ __launch_bounds__(256) void k_spmm64(const uint2* __restrict__ G2,
                                                const int* __restrict__ colsp,
                                                const float* __restrict__ bias,
                                                uint2* __restrict__ H2) {
    const int lane = threadIdx.x & 63;
    const int wave = threadIdx.x >> 6;
    const int v = blockIdx.x * 4 + wave;
    const int* row = &colsp[(size_t)v * ROWI];
    int cnt = row[0];
    int deg = min(cnt, MAXDEG);
    const int mycol = (lane < deg) ? row[8 + lane] : 0;
    const float r = rsqrtf((float)max(cnt, 1));
    const int c = lane & 15;
    const int h = lane >> 4;
    float ax = 0.f, ay = 0.f, az = 0.f, aw = 0.f;
    const int deg16 = deg & ~15;
    for (int j = 0; j < deg16; j += 16) {
        int s0 = __shfl(mycol, j + h);
        int s1 = __shfl(mycol, j + 4 + h);
        int s2 = __shfl(mycol, j + 8 + h);
        int s3 = __shfl(mycol, j + 12 + h);
        uint2 u0 = G2[(size_t)s0 * 16 + c];
        uint2 u1 = G2[(size_t)s1 * 16 + c];
        uint2 u2 = G2[(size_t)s2 * 16 + c];
        uint2 u3 = G2[(size_t)s3 * 16 + c];
        ax += (bl(u0.x) + bl(u1.x)) + (bl(u2.x) + bl(u3.x));
        ay += (bh(u0.x) + bh(u1.x)) + (bh(u2.x) + bh(u3.x));
        az += (bl(u0.y) + bl(u1.y)) + (bl(u2.y) + bl(u3.y));
        aw += (bh(u0.y) + bh(u1.y)) + (bh(u2.y) + bh(u3.y));
    }
    for (int j = deg16; j < deg; j += 4) {
        int idx = j + h;
        int sj = __shfl(mycol, min(idx, deg - 1));
        if (idx < deg) {
            uint2 u = G2[(size_t)sj * 16 + c];
            ax += bl(u.x); ay += bh(u.x); az += bl(u.y); aw += bh(u.y);
        }
    }
    ax += __shfl_xor(ax, 16); ax += __shfl_xor(ax, 32);
    ay += __shfl_xor(ay, 16); ay += __shfl_xor(ay, 32);
    az += __shfl_xor(az, 16); az += __shfl_xor(az, 32);
    aw += __shfl_xor(aw, 16); aw += __shfl_xor(aw, 32);
    if (h == 0) {
        float4 b = *(const float4*)&bias[4 * c];
        __hip_bfloat162 p0 = __float22bfloat162_rn({fmaxf(fmaf(ax, r, b.x), 0.f),
                                                    fmaxf(fmaf(ay, r, b.y), 0.f)});
        __hip_bfloat162 p1 = __float22bfloat162_rn({fmaxf(fmaf(az, r, b.z), 0.f),
                                                    fmaxf(fmaf(aw, r, b.w), 0.f)});
        uint2 o;
        o.x = *(unsigned int*)&p0;
        o.y = *(unsigned int*)&p1;
        H2[(size_t)v * 16 + c] = o;
    }
}

// ---------------- fused pooling + MLP + softmax (block per graph; h2 bf16) ----------------
__global__ __launch_bounds__(256) void k_poolmlp(const unsigned short* __restrict__ h2,
                                                 const int* __restrict__ gid,
                                                 const float* __restrict__ fcW1,
                                                 const float* __restrict__ fcb1,
                                                 const float* __restrict__ fcW2,
                                                 const float* __restrict__ fcb2,
                                                 float* __restrict__ out) {
    __shared__ int se[2];
    __shared__ float part[4][64];
    __shared__ float p[64];
    __shared__ float z[10];
    __shared__ float l[10];
    __shared__ float red[2];
    const int g = blockIdx.x;
    const int tid = threadIdx.x;  // 256
    if (tid < 2) {
        int target = g + tid;  // lower_bound over sorted gid
        int lo = 0, hi = N_NODES;
        while (lo < hi) {
            int mid = (lo + hi) >> 1;
            if (gid[mid] < target) lo = mid + 1; else hi = mid;
        }
        se[tid] = lo;
    }
    __syncthreads();
    const int s = se[0], e = se[1];
    const int c = tid & 63;
    const int w = tid >> 6;
    float acc = 0.f;
    for (int v = s + w; v < e; v += 4)
        acc += __uint_as_float(((unsigned int)h2[(size_t)v * 64 + c]) << 16);
    part[w][c] = acc;
    __syncthreads();
    if (tid < 64) {
        float t = part[0][tid] + part[1][tid] + part[2][tid] + part[3][tid];
        p[tid] = t / (float)max(e - s, 1);
    }
    __syncthreads();
    if (tid < 10) {
        float a = fcb1[tid];
        for (int k = 0; k < 64; k++) a = fmaf(p[k], fcW1[k * 10 + tid], a);
        z[tid] = fmaxf(a, 0.f);
    }
    __syncthreads();
    if (tid < 10) {
        float a = fcb2[tid];
        for (int k = 0; k < 10; k++) a = fmaf(z[k], fcW2[k * 10 + tid], a);
        l[tid] = a;
    }
    __syncthreads();
    if (tid == 0) {
        float m = l[0];
        for (int i = 1; i < 10; i++) m = fmaxf(m, l[i]);
        float ssum = 0.f;
        for (int i = 0; i < 10; i++) ssum += expf(l[i] - m);
        red[0] = m;
        red[1] = ssum;
    }
    __syncthreads();
    if (tid < 10) out[g * 10 + tid] = expf(l[tid] - red[0]) / red[1];
}

// ---------------- host ----------------
extern "C" void kernel_launch(void* const* d_in, const int* in_sizes, int n_in,
                              void* d_out, int out_size, void* d_ws, size_t ws_size,
                              hipStream_t stream) {
    const float* feats = (const float*)d_in[0];
    const int* src = (const int*)d_in[1];
    const int* dst = (const int*)d_in[2];
    const int* gid = (const int*)d_in[3];
    const float* W1 = (const float*)d_in[4];
    const float* b1 = (const float*)d_in[5];
    const float* W2 = (const float*)d_in[6];
    const float* b2 = (const float*)d_in[7];
    const float* fcW1 = (const float*)d_in[8];
    const float* fcb1 = (const float*)d_in[9];
    const float* fcW2 = (const float*)d_in[10];
    const float* fcb2 = (const float*)d_in[11];
    float* out = (float*)d_out;

    char* w = (char*)d_ws;
    size_t off = 0;
    auto alloc = [&](size_t bytes) -> void* {
        void* p = w + off;
        off = (off + bytes + 255) & ~(size_t)255;
        return p;
    };
    int* cnt_out = (int*)alloc(N_NODES * 4);
    int* colsp   = (int*)alloc((size_t)N_NODES * ROWI * 4);                  // 28.8 MB
    int* Pd      = (int*)alloc(NBUCK * SBLK * 4);                            // 400 KB
    int* Ps      = (int*)alloc(NBUCK * SBLK * 4);
    int* Td      = (int*)alloc(NBUCK * 4);
    int* Ts      = (int*)alloc(NBUCK * 4);
    int* Bd      = (int*)alloc((NBUCK + 1) * 4);
    int* Bs      = (int*)alloc((NBUCK + 1) * 4);
    uint2* pb    = (uint2*)alloc((size_t)N_EDGES * 8);                       // 12.8 MB
    int* sb      = (int*)alloc((size_t)N_EDGES * 4);                         // 6.4 MB
    unsigned short* Wt1 = (unsigned short*)alloc(128 * 128 * 2);
    unsigned short* Wt2 = (unsigned short*)alloc(64 * 128 * 2);
    unsigned short* g1 = (unsigned short*)alloc((size_t)N_NODES * 128 * 2);  // bf16
    unsigned short* h1 = (unsigned short*)alloc((size_t)N_NODES * 128 * 2);  // bf16
    unsigned short* g2 = (unsigned short*)alloc((size_t)N_NODES * 64 * 2);   // bf16
    unsigned short* h2 = (unsigned short*)alloc((size_t)N_NODES * 64 * 2);   // bf16

    // build pipeline (no scattered device atomics, no memsets needed)
    k_hist2<<<SBLK + NB_PREP, 256, 0, stream>>>(src, dst, Pd, Ps, W1, W2, Wt1, Wt2);
    k_scanA<<<2 * NBUCK, 128, 0, stream>>>(Pd, Ps, Td, Ts);
    k_scanB<<<1, 1024, 0, stream>>>(Td, Ts, Bd, Bs);
    k_scatter<<<SBLK, 256, 0, stream>>>(src, dst, Pd, Ps, Bd, Bs, pb, sb);
    k_finalize<<<NBUCK, 256, 0, stream>>>(pb, Bd, sb, Bs, colsp, cnt_out);

    // layer 1
    k_gemm_mfma<128, false><<<dim3(N_NODES / 32, 2), 256, 0, stream>>>(feats, Wt1, cnt_out, g1);
    k_spmm128<<<N_NODES / 4, 256, 0, stream>>>((const uint2*)g1, colsp, b1, (uint2*)h1);

    // layer 2
    k_gemm_mfma<64, true><<<dim3(N_NODES / 32, 1), 256, 0, stream>>>(h1, Wt2, cnt_out, g2);
    k_spmm64<<<N_NODES / 4, 256, 0, stream>>>((const uint2*)g2, colsp, b2, (uint2*)h2);

    k_poolmlp<<<N_GRAPHS, 256, 0, stream>>>(h2, gid, fcW1, fcb1, fcW2, fcb2, out);
}

// Round 8
// 355.531 us; speedup vs baseline: 1.3335x; 1.1226x over previous
//
#include <hip/hip_runtime.h>
#include <hip/hip_bf16.h>

#define N_NODES 100000
#define N_EDGES 1600000
#define N_GRAPHS 128
#define IN_F 128
#define H_F 128
#define OUT_F 64
#define HID 10
#define NCLS 10
#define MAXDEG 64   // in-degree ~ Poisson(16); P(deg>64) ~ 1e-20 per node
#define XPAD 136    // LDS row stride in bf16 (pad 128 -> 136: 16-way conflict -> free 2-way)
#define ROWI 72     // adjacency row stride in ints: [0]=count, [8..71]=neighbors (288 B)
#define BSH 7                     // bucket = node >> 7 (128-node windows)
#define NBUCK 782                 // ceil(100000/128)
#define SBLK 128                  // edge partitions for hist/scatter
#define EPB (N_EDGES / SBLK)      // 12500, exact
#define NB_PREP 4

typedef __attribute__((ext_vector_type(8))) short bf16x8;
typedef __attribute__((ext_vector_type(4))) float f32x4;

__device__ __forceinline__ float bl(unsigned int u) { return __uint_as_float(u << 16); }
__device__ __forceinline__ float bh(unsigned int u) { return __uint_as_float(u & 0xffff0000u); }

// ---------------- phase 1: LDS-privatized bucket histograms (dst & src) + weight prep ----------------
__global__ __launch_bounds__(1024) void k_hist2(const int* __restrict__ src, const int* __restrict__ dst,
                                                int* __restrict__ Pd, int* __restrict__ Ps,
                                                const float* __restrict__ W1, const float* __restrict__ W2,
                                                unsigned short* __restrict__ Wt1, unsigned short* __restrict__ Wt2) {
    __shared__ int hd[NBUCK];
    __shared__ int hs[NBUCK];
    const int blk = blockIdx.x;
    if (blk < SBLK) {
        for (int i = threadIdx.x; i < NBUCK; i += 1024) { hd[i] = 0; hs[i] = 0; }
        __syncthreads();
        const int base = blk * EPB;
        for (int i = threadIdx.x; i < EPB; i += 1024) {
            atomicAdd(&hd[dst[base + i] >> BSH], 1);
            atomicAdd(&hs[src[base + i] >> BSH], 1);
        }
        __syncthreads();
        for (int b = threadIdx.x; b < NBUCK; b += 1024) {
            Pd[b * SBLK + blk] = hd[b];
            Ps[b * SBLK + blk] = hs[b];
        }
    } else {
        int t = (blk - SBLK) * 1024 + threadIdx.x;
        const int stride = NB_PREP * 1024;
        for (int i = t; i < 128 * 128; i += stride) {
            int c = i >> 7, k = i & 127;
            __hip_bfloat16 v = __float2bfloat16(W1[k * 128 + c]);
            Wt1[i] = *(unsigned short*)&v;
        }
        for (int i = t; i < 64 * 128; i += stride) {
            int c = i >> 7, k = i & 127;
            __hip_bfloat16 v = __float2bfloat16(W2[k * 64 + c]);
            Wt2[i] = *(unsigned short*)&v;
        }
    }
}

// ---------------- phase 2a: per-bucket scan across blocks (exclusive), emit totals ----------------
__global__ __launch_bounds__(128) void k_scanA(int* __restrict__ Pd, int* __restrict__ Ps,
                                               int* __restrict__ Td, int* __restrict__ Ts) {
    __shared__ int sc[128];
    const int b = blockIdx.x;
    const int t = threadIdx.x;
    int* P = (b < NBUCK) ? Pd : Ps;
    int* T = (b < NBUCK) ? Td : Ts;
    const int bb = (b < NBUCK) ? b : b - NBUCK;
    int v = P[bb * SBLK + t];
    sc[t] = v;
    __syncthreads();
    for (int off = 1; off < 128; off <<= 1) {
        int u = (t >= off) ? sc[t - off] : 0;
        __syncthreads();
        sc[t] += u;
        __syncthreads();
    }
    P[bb * SBLK + t] = sc[t] - v;    // exclusive within bucket
    if (t == 127) T[bb] = sc[127];
}

// ---------------- phase 2b: scan bucket totals -> global bases (with total at [NBUCK]) ----------------
__global__ __launch_bounds__(1024) void k_scanB(const int* __restrict__ Td, const int* __restrict__ Ts,
                                                int* __restrict__ Bd, int* __restrict__ Bs) {
    __shared__ int sc[1024];
    const int t = threadIdx.x;
    int v = (t < NBUCK) ? Td[t] : 0;
    sc[t] = v;
    __syncthreads();
    for (int off = 1; off < 1024; off <<= 1) {
        int u = (t >= off) ? sc[t - off] : 0;
        __syncthreads();
        sc[t] += u;
        __syncthreads();
    }
    if (t < NBUCK) Bd[t] = sc[t] - v;
    if (t == NBUCK - 1) Bd[NBUCK] = sc[t];
    __syncthreads();
    int v2 = (t < NBUCK) ? Ts[t] : 0;
    sc[t] = v2;
    __syncthreads();
    for (int off = 1; off < 1024; off <<= 1) {
        int u = (t >= off) ? sc[t - off] : 0;
        __syncthreads();
        sc[t] += u;
        __syncthreads();
    }
    if (t < NBUCK) Bs[t] = sc[t] - v2;
    if (t == NBUCK - 1) Bs[NBUCK] = sc[t];
}

// ---------------- phase 3: bucketed scatter, role-split, packed payloads ----------------
// blocks [0,SBLK): dst-bucketed pairs packed as (src<<7)|(dst&127)  (src < 2^17)
// blocks [SBLK,2*SBLK): src-bucketed bytes (src&127)
__global__ __launch_bounds__(1024) void k_scatter(const int* __restrict__ src, const int* __restrict__ dst,
                                                  const int* __restrict__ Pd, const int* __restrict__ Ps,
                                                  const int* __restrict__ Bd, const int* __restrict__ Bs,
                                                  unsigned int* __restrict__ pb, unsigned char* __restrict__ sb) {
    __shared__ int tk[NBUCK];
    const int b = blockIdx.x;
    const bool isPb = b < SBLK;
    const int blk = isPb ? b : b - SBLK;
    for (int i = threadIdx.x; i < NBUCK; i += 1024) tk[i] = 0;
    __syncthreads();
    const int base = blk * EPB;
    if (isPb) {
        for (int i = threadIdx.x; i < EPB; i += 1024) {
            int d = dst[base + i];
            int s = src[base + i];
            int bd = d >> BSH;
            int t = atomicAdd(&tk[bd], 1);
            pb[Bd[bd] + Pd[bd * SBLK + blk] + t] = ((unsigned)s << 7) | (unsigned)(d & 127);
        }
    } else {
        for (int i = threadIdx.x; i < EPB; i += 1024) {
            int s = src[base + i];
            int bs = s >> BSH;
            int t = atomicAdd(&tk[bs], 1);
            sb[Bs[bs] + Ps[bs * SBLK + blk] + t] = (unsigned char)(s & 127);
        }
    }
}

// ---------------- phase 4: per-window adjacency build in LDS + coalesced writeout + cnt_out ----------------
__global__ __launch_bounds__(256) void k_finalize(const unsigned int* __restrict__ pb, const int* __restrict__ Bd,
                                                  const unsigned char* __restrict__ sb, const int* __restrict__ Bs,
                                                  int* __restrict__ colsp, int* __restrict__ cnt_out) {
    __shared__ int cnt[128];
    __shared__ int adj[128 * 65];   // stride 65 spreads LDS banks
    __shared__ int h[128];
    const int b = blockIdx.x;
    const int tid = threadIdx.x;
    if (tid < 128) { cnt[tid] = 0; h[tid] = 0; }
    __syncthreads();
    {
        const int s0 = Bd[b], s1 = Bd[b + 1];
        for (int i = s0 + tid; i < s1; i += 256) {
            unsigned int p = pb[i];
            int loc = p & 127;
            int t = atomicAdd(&cnt[loc], 1);
            if (t < MAXDEG) adj[loc * 65 + t] = (int)(p >> 7);
        }
    }
    {
        const int s0 = Bs[b], s1 = Bs[b + 1];
        for (int i = s0 + tid; i < s1; i += 256)
            atomicAdd(&h[sb[i]], 1);
    }
    __syncthreads();
    const int node0 = b << BSH;
    for (int i = tid; i < 128 * ROWI; i += 256) {
        int row = i / ROWI;
        int slot = i - row * ROWI;
        int node = node0 + row;
        if (node >= N_NODES) continue;
        int val = (slot == 0) ? cnt[row] : ((slot >= 8) ? adj[row * 65 + (slot - 8)] : 0);
        colsp[(size_t)node * ROWI + slot] = val;
    }
    int node = node0 + tid;
    if (tid < 128 && node < N_NODES) cnt_out[node] = h[tid];
}

// ---------------- MFMA GEMM: G[v, cbase..+63] = rsqrt(deg_out[v]) * (X[v,:] @ W[:, cbase..+63])
template <int TOTF, bool XBF16>
__global__ __launch_bounds__(256) void k_gemm_mfma(const void* __restrict__ Xv,
                                                   const unsigned short* __restrict__ Wt,
                                                   const int* __restrict__ cnt_out,
                                                   unsigned short* __restrict__ Gout) {
    __shared__ __align__(16) unsigned short Xs[32 * XPAD];
    __shared__ __align__(16) unsigned short Ws[64 * XPAD];
    const int tid = threadIdx.x;
    const int cbase = blockIdx.y * 64;
    const int row0 = blockIdx.x * 32;  // N_NODES % 32 == 0

    if constexpr (XBF16) {
        const uint2* X2 = (const uint2*)Xv;  // row = 32 uint2 (128 bf16)
#pragma unroll
        for (int j = 0; j < 4; j++) {
            int i = tid + 256 * j;
            int r = i >> 5, kk = i & 31;
            uint2 u = X2[(size_t)(row0 + r) * 32 + kk];
            *(uint2*)&Xs[r * XPAD + kk * 4] = u;
        }
    } else {
        const float4* X4 = (const float4*)Xv;  // row = 32 float4
#pragma unroll
        for (int j = 0; j < 4; j++) {
            int i = tid + 256 * j;
            int r = i >> 5, k4 = i & 31;
            float4 x = X4[(size_t)(row0 + r) * 32 + k4];
            __hip_bfloat162 lo = __float22bfloat162_rn({x.x, x.y});
            __hip_bfloat162 hi = __float22bfloat162_rn({x.z, x.w});
            uint2 u;
            u.x = *(unsigned int*)&lo;
            u.y = *(unsigned int*)&hi;
            *(uint2*)&Xs[r * XPAD + k4 * 4] = u;
        }
    }
    {
        const uint2* W2 = (const uint2*)Wt;  // row = 32 uint2
#pragma unroll
        for (int j = 0; j < 8; j++) {
            int i = tid + 256 * j;
            int c = i >> 5, kk = i & 31;
            uint2 u = W2[(size_t)(cbase + c) * 32 + kk];
            *(uint2*)&Ws[c * XPAD + kk * 4] = u;
        }
    }
    __syncthreads();

    const int lane = tid & 63;
    const int wv = tid >> 6;
    const int m = lane & 15;
    const int q = lane >> 4;
    const int roff = (wv & 1) * 16;
    const int coff = (wv >> 1) * 32;

    f32x4 acc0 = {0.f, 0.f, 0.f, 0.f}, acc1 = {0.f, 0.f, 0.f, 0.f};
#pragma unroll
    for (int ks = 0; ks < 4; ks++) {
        int kb = ks * 32 + q * 8;
        bf16x8 a  = *(const bf16x8*)&Xs[(roff + m) * XPAD + kb];
        bf16x8 b0 = *(const bf16x8*)&Ws[(coff + m) * XPAD + kb];
        bf16x8 b1 = *(const bf16x8*)&Ws[(coff + 16 + m) * XPAD + kb];
        acc0 = __builtin_amdgcn_mfma_f32_16x16x32_bf16(a, b0, acc0, 0, 0, 0);
        acc1 = __builtin_amdgcn_mfma_f32_16x16x32_bf16(a, b1, acc1, 0, 0, 0);
    }
#pragma unroll
    for (int r = 0; r < 4; r++) {
        int row = row0 + roff + q * 4 + r;
        float s = rsqrtf((float)max(cnt_out[row], 1));
        int col0 = cbase + coff + m;
        __hip_bfloat16 o0 = __float2bfloat16(acc0[r] * s);
        __hip_bfloat16 o1 = __float2bfloat16(acc1[r] * s);
        Gout[(size_t)row * TOTF + col0]      = *(unsigned short*)&o0;
        Gout[(size_t)row * TOTF + col0 + 16] = *(unsigned short*)&o1;
    }
}

// ---------------- SpMM F=128: half-wave per neighbor, uint2 gathers ----------------
__global__ __launch_bounds__(256) void k_spmm128(const uint2* __restrict__ G2,
                                                 const int* __restrict__ colsp,
                                                 const float* __restrict__ bias,
                                                 uint2* __restrict__ H2) {
    const int lane = threadIdx.x & 63;
    const int wave = threadIdx.x >> 6;
    const int v = blockIdx.x * 4 + wave;   // N_NODES % 4 == 0
    const int* row = &colsp[(size_t)v * ROWI];
    int cnt = row[0];
    int deg = min(cnt, MAXDEG);
    const int mycol = (lane < deg) ? row[8 + lane] : 0;
    const float r = rsqrtf((float)max(cnt, 1));
    const int c = lane & 31;
    const int h = lane >> 5;
    float ax = 0.f, ay = 0.f, az = 0.f, aw = 0.f;
    const int deg8 = deg & ~7;
    for (int j = 0; j < deg8; j += 8) {
        int s0 = __shfl(mycol, j + h);
        int s1 = __shfl(mycol, j + 2 + h);
        int s2 = __shfl(mycol, j + 4 + h);
        int s3 = __shfl(mycol, j + 6 + h);
        uint2 u0 = G2[(size_t)s0 * 32 + c];
        uint2 u1 = G2[(size_t)s1 * 32 + c];
        uint2 u2 = G2[(size_t)s2 * 32 + c];
        uint2 u3 = G2[(size_t)s3 * 32 + c];
        ax += (bl(u0.x) + bl(u1.x)) + (bl(u2.x) + bl(u3.x));
        ay += (bh(u0.x) + bh(u1.x)) + (bh(u2.x) + bh(u3.x));
        az += (bl(u0.y) + bl(u1.y)) + (bl(u2.y) + bl(u3.y));
        aw += (bh(u0.y) + bh(u1.y)) + (bh(u2.y) + bh(u3.y));
    }
    for (int j = deg8; j < deg; j += 2) {
        int idx = j + h;
        int sj = __shfl(mycol, min(idx, deg - 1));
        if (idx < deg) {
            uint2 u = G2[(size_t)sj * 32 + c];
            ax += bl(u.x); ay += bh(u.x); az += bl(u.y); aw += bh(u.y);
        }
    }
    ax += __shfl_xor(ax, 32);
    ay += __shfl_xor(ay, 32);
    az += __shfl_xor(az, 32);
    aw += __shfl_xor(aw, 32);
    if (h == 0) {
        float4 b = *(const float4*)&bias[4 * c];
        __hip_bfloat162 p0 = __float22bfloat162_rn({fmaxf(fmaf(ax, r, b.x), 0.f),
                                                    fmaxf(fmaf(ay, r, b.y), 0.f)});
        __hip_bfloat162 p1 = __float22bfloat162_rn({fmaxf(fmaf(az, r, b.z), 0.f),
                                                    fmaxf(fmaf(aw, r, b.w), 0.f)});
        uint2 o;
        o.x = *(unsigned int*)&p0;
        o.y = *(unsigned int*)&p1;
        H2[(size_t)v * 32 + c] = o;
    }
}

// ---------------- SpMM F=64: quarter-wave per neighbor, uint2 gathers ----------------
__global__ __launch_bounds__(256) void k_spmm64(const uint2* __restrict__ G2,
                                                const int* __restrict__ colsp,
                                                const float* __restrict__ bias,
                                                uint2* __restrict__ H2) {
    const int lane = threadIdx.x & 63;
    const int wave = threadIdx.x >> 6;
    const int v = blockIdx.x * 4 + wave;
    const int* row = &colsp[(size_t)v * ROWI];
    int cnt = row[0];
    int deg = min(cnt, MAXDEG);
    const int mycol = (lane < deg) ? row[8 + lane] : 0;
    const float r = rsqrtf((float)max(cnt, 1));
    const int c = lane & 15;
    const int h = lane >> 4;
    float ax = 0.f, ay = 0.f, az = 0.f, aw = 0.f;
    const int deg16 = deg & ~15;
    for (int j = 0; j < deg16; j += 16) {
        int s0 = __shfl(mycol, j + h);
        int s1 = __shfl(mycol, j + 4 + h);
        int s2 = __shfl(mycol, j + 8 + h);
        int s3 = __shfl(mycol, j + 12 + h);
        uint2 u0 = G2[(size_t)s0 * 16 + c];
        uint2 u1 = G2[(size_t)s1 * 16 + c];
        uint2 u2 = G2[(size_t)s2 * 16 + c];
        uint2 u3 = G2[(size_t)s3 * 16 + c];
        ax += (bl(u0.x) + bl(u1.x)) + (bl(u2.x) + bl(u3.x));
        ay += (bh(u0.x) + bh(u1.x)) + (bh(u2.x) + bh(u3.x));
        az += (bl(u0.y) + bl(u1.y)) + (bl(u2.y) + bl(u3.y));
        aw += (bh(u0.y) + bh(u1.y)) + (bh(u2.y) + bh(u3.y));
    }
    for (int j = deg16; j < deg; j += 4) {
        int idx = j + h;
        int sj = __shfl(mycol, min(idx, deg - 1));
        if (idx < deg) {
            uint2 u = G2[(size_t)sj * 16 + c];
            ax += bl(u.x); ay += bh(u.x); az += bl(u.y); aw += bh(u.y);
        }
    }
    ax += __shfl_xor(ax, 16); ax += __shfl_xor(ax, 32);
    ay += __shfl_xor(ay, 16); ay += __shfl_xor(ay, 32);
    az += __shfl_xor(az, 16); az += __shfl_xor(az, 32);
    aw += __shfl_xor(aw, 16); aw += __shfl_xor(aw, 32);
    if (h == 0) {
        float4 b = *(const float4*)&bias[4 * c];
        __hip_bfloat162 p0 = __float22bfloat162_rn({fmaxf(fmaf(ax, r, b.x), 0.f),
                                                    fmaxf(fmaf(ay, r, b.y), 0.f)});
        __hip_bfloat162 p1 = __float22bfloat162_rn({fmaxf(fmaf(az, r, b.z), 0.f),
                                                    fmaxf(fmaf(aw, r, b.w), 0.f)});
        uint2 o;
        o.x = *(unsigned int*)&p0;
        o.y = *(unsigned int*)&p1;
        H2[(size_t)v * 16 + c] = o;
    }
}

// ---------------- fused pooling + MLP + softmax (block per graph; h2 bf16) ----------------
__global__ __launch_bounds__(256) void k_poolmlp(const unsigned short* __restrict__ h2,
                                                 const int* __restrict__ gid,
                                                 const float* __restrict__ fcW1,
                                                 const float* __restrict__ fcb1,
                                                 const float* __restrict__ fcW2,
                                                 const float* __restrict__ fcb2,
                                                 float* __restrict__ out) {
    __shared__ int se[2];
    __shared__ float part[4][64];
    __shared__ float p[64];
    __shared__ float z[10];
    __shared__ float l[10];
    __shared__ float red[2];
    const int g = blockIdx.x;
    const int tid = threadIdx.x;  // 256
    if (tid < 2) {
        int target = g + tid;  // lower_bound over sorted gid
        int lo = 0, hi = N_NODES;
        while (lo < hi) {
            int mid = (lo + hi) >> 1;
            if (gid[mid] < target) lo = mid + 1; else hi = mid;
        }
        se[tid] = lo;
    }
    __syncthreads();
    const int s = se[0], e = se[1];
    const int c = tid & 63;
    const int w = tid >> 6;
    float acc = 0.f;
    for (int v = s + w; v < e; v += 4)
        acc += __uint_as_float(((unsigned int)h2[(size_t)v * 64 + c]) << 16);
    part[w][c] = acc;
    __syncthreads();
    if (tid < 64) {
        float t = part[0][tid] + part[1][tid] + part[2][tid] + part[3][tid];
        p[tid] = t / (float)max(e - s, 1);
    }
    __syncthreads();
    if (tid < 10) {
        float a = fcb1[tid];
        for (int k = 0; k < 64; k++) a = fmaf(p[k], fcW1[k * 10 + tid], a);
        z[tid] = fmaxf(a, 0.f);
    }
    __syncthreads();
    if (tid < 10) {
        float a = fcb2[tid];
        for (int k = 0; k < 10; k++) a = fmaf(z[k], fcW2[k * 10 + tid], a);
        l[tid] = a;
    }
    __syncthreads();
    if (tid == 0) {
        float m = l[0];
        for (int i = 1; i < 10; i++) m = fmaxf(m, l[i]);
        float ssum = 0.f;
        for (int i = 0; i < 10; i++) ssum += expf(l[i] - m);
        red[0] = m;
        red[1] = ssum;
    }
    __syncthreads();
    if (tid < 10) out[g * 10 + tid] = expf(l[tid] - red[0]) / red[1];
}

// ---------------- host ----------------
extern "C" void kernel_launch(void* const* d_in, const int* in_sizes, int n_in,
                              void* d_out, int out_size, void* d_ws, size_t ws_size,
                              hipStream_t stream) {
    const float* feats = (const float*)d_in[0];
    const int* src = (const int*)d_in[1];
    const int* dst = (const int*)d_in[2];
    const int* gid = (const int*)d_in[3];
    const float* W1 = (const float*)d_in[4];
    const float* b1 = (const float*)d_in[5];
    const float* W2 = (const float*)d_in[6];
    const float* b2 = (const float*)d_in[7];
    const float* fcW1 = (const float*)d_in[8];
    const float* fcb1 = (const float*)d_in[9];
    const float* fcW2 = (const float*)d_in[10];
    const float* fcb2 = (const float*)d_in[11];
    float* out = (float*)d_out;

    char* w = (char*)d_ws;
    size_t off = 0;
    auto alloc = [&](size_t bytes) -> void* {
        void* p = w + off;
        off = (off + bytes + 255) & ~(size_t)255;
        return p;
    };
    int* cnt_out = (int*)alloc(N_NODES * 4);
    int* colsp   = (int*)alloc((size_t)N_NODES * ROWI * 4);                  // 28.8 MB
    int* Pd      = (int*)alloc(NBUCK * SBLK * 4);                            // 400 KB
    int* Ps      = (int*)alloc(NBUCK * SBLK * 4);
    int* Td      = (int*)alloc(NBUCK * 4);
    int* Ts      = (int*)alloc(NBUCK * 4);
    int* Bd      = (int*)alloc((NBUCK + 1) * 4);
    int* Bs      = (int*)alloc((NBUCK + 1) * 4);
    unsigned int* pb  = (unsigned int*)alloc((size_t)N_EDGES * 4);           // 6.4 MB packed
    unsigned char* sb = (unsigned char*)alloc((size_t)N_EDGES);              // 1.6 MB
    unsigned short* Wt1 = (unsigned short*)alloc(128 * 128 * 2);
    unsigned short* Wt2 = (unsigned short*)alloc(64 * 128 * 2);
    unsigned short* g1 = (unsigned short*)alloc((size_t)N_NODES * 128 * 2);  // bf16
    unsigned short* h1 = (unsigned short*)alloc((size_t)N_NODES * 128 * 2);  // bf16
    unsigned short* g2 = (unsigned short*)alloc((size_t)N_NODES * 64 * 2);   // bf16
    unsigned short* h2 = (unsigned short*)alloc((size_t)N_NODES * 64 * 2);   // bf16

    // build pipeline (no scattered device atomics, no memsets needed)
    k_hist2<<<SBLK + NB_PREP, 1024, 0, stream>>>(src, dst, Pd, Ps, W1, W2, Wt1, Wt2);
    k_scanA<<<2 * NBUCK, 128, 0, stream>>>(Pd, Ps, Td, Ts);
    k_scanB<<<1, 1024, 0, stream>>>(Td, Ts, Bd, Bs);
    k_scatter<<<2 * SBLK, 1024, 0, stream>>>(src, dst, Pd, Ps, Bd, Bs, pb, sb);
    k_finalize<<<NBUCK, 256, 0, stream>>>(pb, Bd, sb, Bs, colsp, cnt_out);

    // layer 1
    k_gemm_mfma<128, false><<<dim3(N_NODES / 32, 2), 256, 0, stream>>>(feats, Wt1, cnt_out, g1);
    k_spmm128<<<N_NODES / 4, 256, 0, stream>>>((const uint2*)g1, colsp, b1, (uint2*)h1);

    // layer 2
    k_gemm_mfma<64, true><<<dim3(N_NODES / 32, 1), 256, 0, stream>>>(h1, Wt2, cnt_out, g2);
    k_spmm64<<<N_NODES / 4, 256, 0, stream>>>((const uint2*)g2, colsp, b2, (uint2*)h2);

    k_poolmlp<<<N_GRAPHS, 256, 0, stream>>>(h2, gid, fcW1, fcb1, fcW2, fcb2, out);
}